// Round 5
// baseline (1286.777 us; speedup 1.0000x reference)
//
#include <hip/hip_runtime.h>
#include <math.h>

#define HW    1024   // 32*32 pixels
#define CIN   1024
#define CCTX  28
#define CALL  1052
#define COUT  2048
#define CCHNK 512
#define NCHNK 4

// ---------------------------------------------------------------------------
// Kernel 1: per-pixel feature L2 norm (clamped, F.normalize style)
// ---------------------------------------------------------------------------
__global__ void pnorm_kernel(const float* __restrict__ src, const float* __restrict__ tgt,
                             float* __restrict__ pnorm) {
    int img = blockIdx.x;
    int p = blockIdx.y * 64 + threadIdx.x;
    const float* feat = (img < 4) ? src + (size_t)img * CIN * HW
                                  : tgt + (size_t)(img - 4) * CIN * HW;
    float ss = 0.f;
    for (int c = 0; c < CIN; ++c) {
        float v = feat[(size_t)c * HW + p];
        ss = fmaf(v, v, ss);
    }
    pnorm[img * HW + p] = fmaxf(sqrtf(ss), 1e-12f);
}

// ---------------------------------------------------------------------------
// Kernel 2: shifted local correlations on L2-normalized features.
// ---------------------------------------------------------------------------
__global__ void ctx_kernel(const float* __restrict__ src, const float* __restrict__ tgt,
                           const float* __restrict__ pnorm, float* __restrict__ ctx) {
    int img = blockIdx.x;
    int y = blockIdx.y;
    int tid = threadIdx.x;
    int o = tid >> 5;   // 0..27
    int x = tid & 31;
    const float* feat = (img < 4) ? src + (size_t)img * CIN * HW
                                  : tgt + (size_t)(img - 4) * CIN * HW;
    int g = o / 7, i = o % 7;
    int r, c;
    if (g == 0)      { r = i; c = i; }
    else if (g == 1) { r = i; c = 3; }
    else if (g == 2) { r = i; c = 6 - i; }
    else             { r = 3; c = i; }
    int y2 = y + r - 3, x2 = x + c - 3;
    int p = y * 32 + x;
    float outv = 0.f;
    if (y2 >= 0 && y2 < 32 && x2 >= 0 && x2 < 32) {
        int p2 = y2 * 32 + x2;
        const float* f0 = feat + p;
        const float* f1 = feat + p2;
        float acc = 0.f;
        for (int ch = 0; ch < CIN; ++ch)
            acc = fmaf(f0[(size_t)ch * HW], f1[(size_t)ch * HW], acc);
        outv = acc / (pnorm[img * HW + p] * pnorm[img * HW + p2]);
    }
    ctx[((size_t)img * CCTX + o) * HW + p] = outv;
}

// ---------------------------------------------------------------------------
// Kernel 3: conv chunk GEMM, 128x128 tile, 8x8/thread (2x2 groups of 4x4),
// double-buffered LDS. grid (8 nblk, 4 mblk, 8 img), 256 threads.
// ---------------------------------------------------------------------------
template <bool FIRST>
__global__ __launch_bounds__(256) void conv_chunk(const float* __restrict__ src,
                                                  const float* __restrict__ tgt,
                                                  const float* __restrict__ ctxb,
                                                  const float* __restrict__ w,
                                                  const float* __restrict__ bias,
                                                  float* __restrict__ chunkbuf,
                                                  float* __restrict__ nrm_parts,
                                                  int c0) {
    __shared__ float As[2][16][128];   // W tile, [k][m]
    __shared__ float Bs[2][16][128];   // X tile, [k][n]
    int img = blockIdx.z;
    int mb = blockIdx.y;                    // 0..3 (128 rows each)
    int m0g = c0 + mb * 128;
    int n0 = blockIdx.x * 128;
    const float* feat = (img < 4) ? src + (size_t)img * CIN * HW
                                  : tgt + (size_t)(img - 4) * CIN * HW;
    const float* ctxi = ctxb + (size_t)img * CCTX * HW;
    int tid = threadIdx.x;
    int tm = tid >> 4, tn = tid & 15;
    int arow = tid >> 1, ak8 = (tid & 1) * 8;   // A stage: 128 rows x 2 k-octets
    int brow = tid >> 4, bc = (tid & 15) * 8;   // B stage: 16 rows x 16 col-octets

    float4 w0, w1, b0r, b1r;
    auto loadA = [&](int k0) {
        const float* wp = w + (size_t)(m0g + arow) * CALL + k0 + ak8;
        w0 = (k0 + ak8 + 4 <= CALL) ? *(const float4*)(wp)
                                    : make_float4(0.f, 0.f, 0.f, 0.f);
        w1 = (k0 + ak8 + 8 <= CALL) ? *(const float4*)(wp + 4)
                                    : make_float4(0.f, 0.f, 0.f, 0.f);
    };
    auto loadB = [&](int k0) {
        int crow = k0 + brow;
        if (crow < CIN) {
            const float* rp = feat + (size_t)crow * HW + n0 + bc;
            b0r = *(const float4*)(rp);
            b1r = *(const float4*)(rp + 4);
        } else if (crow < CALL) {
            const float* rp = ctxi + (size_t)(crow - CIN) * HW + n0 + bc;
            b0r = *(const float4*)(rp);
            b1r = *(const float4*)(rp + 4);
        } else {
            b0r = make_float4(0.f, 0.f, 0.f, 0.f); b1r = b0r;
        }
    };
    auto storeLDS = [&](int buf) {
        As[buf][ak8 + 0][arow] = w0.x; As[buf][ak8 + 1][arow] = w0.y;
        As[buf][ak8 + 2][arow] = w0.z; As[buf][ak8 + 3][arow] = w0.w;
        As[buf][ak8 + 4][arow] = w1.x; As[buf][ak8 + 5][arow] = w1.y;
        As[buf][ak8 + 6][arow] = w1.z; As[buf][ak8 + 7][arow] = w1.w;
        *(float4*)&Bs[buf][brow][bc] = b0r;
        *(float4*)&Bs[buf][brow][bc + 4] = b1r;
    };

    loadA(0); loadB(0); storeLDS(0);
    __syncthreads();

    float acc[2][2][4][4] = {};
    const int NT = 66;                       // ceil(1052/16)
    for (int t = 0; t < NT; ++t) {
        int cur = t & 1;
        if (t + 1 < NT) { loadA((t + 1) * 16); loadB((t + 1) * 16); }
#pragma unroll
        for (int k = 0; k < 16; ++k) {
            float4 a0 = *(const float4*)&As[cur][k][tm * 4];
            float4 a1 = *(const float4*)&As[cur][k][64 + tm * 4];
            float4 p0 = *(const float4*)&Bs[cur][k][tn * 4];
            float4 p1 = *(const float4*)&Bs[cur][k][64 + tn * 4];
            float av0[4] = {a0.x, a0.y, a0.z, a0.w};
            float av1[4] = {a1.x, a1.y, a1.z, a1.w};
            float bv0[4] = {p0.x, p0.y, p0.z, p0.w};
            float bv1[4] = {p1.x, p1.y, p1.z, p1.w};
#pragma unroll
            for (int i = 0; i < 4; ++i)
#pragma unroll
                for (int j = 0; j < 4; ++j) {
                    acc[0][0][i][j] = fmaf(av0[i], bv0[j], acc[0][0][i][j]);
                    acc[0][1][i][j] = fmaf(av0[i], bv1[j], acc[0][1][i][j]);
                    acc[1][0][i][j] = fmaf(av1[i], bv0[j], acc[1][0][i][j]);
                    acc[1][1][i][j] = fmaf(av1[i], bv1[j], acc[1][1][i][j]);
                }
        }
        if (t + 1 < NT) storeLDS(cur ^ 1);
        __syncthreads();
    }

    // epilogue: bias + relu, store, per-pixel sum-of-squares partials
    float psum[2][4] = {};
#pragma unroll
    for (int ih = 0; ih < 2; ++ih)
#pragma unroll
    for (int i = 0; i < 4; ++i) {
        int oloc = mb * 128 + ih * 64 + tm * 4 + i;
        float bv = bias[c0 + oloc];
        float* op = chunkbuf + ((size_t)img * CCHNK + oloc) * HW + n0;
#pragma unroll
        for (int jh = 0; jh < 2; ++jh) {
            float4 o;
            o.x = fmaxf(acc[ih][jh][i][0] + bv, 0.f);
            o.y = fmaxf(acc[ih][jh][i][1] + bv, 0.f);
            o.z = fmaxf(acc[ih][jh][i][2] + bv, 0.f);
            o.w = fmaxf(acc[ih][jh][i][3] + bv, 0.f);
            *(float4*)(op + jh * 64 + tn * 4) = o;
            psum[jh][0] = fmaf(o.x, o.x, psum[jh][0]);
            psum[jh][1] = fmaf(o.y, o.y, psum[jh][1]);
            psum[jh][2] = fmaf(o.z, o.z, psum[jh][2]);
            psum[jh][3] = fmaf(o.w, o.w, psum[jh][3]);
        }
    }
    // reduce over tm via LDS (reuse As[0]; loop ended with a barrier)
#pragma unroll
    for (int jh = 0; jh < 2; ++jh)
#pragma unroll
    for (int j = 0; j < 4; ++j)
        As[0][tm][jh * 64 + tn * 4 + j] = psum[jh][j];
    __syncthreads();
    if (tid < 128) {
        float s = 0.f;
#pragma unroll
        for (int r = 0; r < 16; ++r) s += As[0][r][tid];
        float* np = nrm_parts + ((size_t)img * 4 + mb) * HW + n0 + tid;
        if (FIRST) *np = s; else *np += s;
    }
}

// ---------------------------------------------------------------------------
// Kernel 4: correlation chunk GEMM, 128(t)x128(s) tile, 8x8/thread, dbuf.
// MODE 0: corrT = acc ; MODE 1: corrT += acc ;
// MODE 2: corrT = (corrT+acc)/(nt*ns), emit smax/tmax partials.
// grid (8 sblk, 8 tblk, 4 b), 256 threads.
// ---------------------------------------------------------------------------
template <int MODE>
__global__ __launch_bounds__(256) void corr_chunk(const float* __restrict__ chunkbuf,
                                                  const float* __restrict__ nrm_sq,
                                                  float* __restrict__ corrT,
                                                  float* __restrict__ spar,
                                                  float* __restrict__ tpar) {
    __shared__ float As[2][16][128];   // tgt [k][t]
    __shared__ float Bs[2][16][128];   // src [k][s]
    int b = blockIdx.z;
    int t0 = blockIdx.y * 128;
    int s0 = blockIdx.x * 128;
    const float* tg = chunkbuf + (size_t)(4 + b) * CCHNK * HW;
    const float* sr = chunkbuf + (size_t)b * CCHNK * HW;
    int tid = threadIdx.x;
    int tm = tid >> 4, tn = tid & 15;
    int srow = tid >> 4, sc = (tid & 15) * 8;

    float4 a0r, a1r, b0r, b1r;
    auto loadAB = [&](int k0) {
        const float* ap = tg + (size_t)(k0 + srow) * HW + t0 + sc;
        a0r = *(const float4*)(ap);
        a1r = *(const float4*)(ap + 4);
        const float* bp = sr + (size_t)(k0 + srow) * HW + s0 + sc;
        b0r = *(const float4*)(bp);
        b1r = *(const float4*)(bp + 4);
    };
    auto storeLDS = [&](int buf) {
        *(float4*)&As[buf][srow][sc] = a0r;
        *(float4*)&As[buf][srow][sc + 4] = a1r;
        *(float4*)&Bs[buf][srow][sc] = b0r;
        *(float4*)&Bs[buf][srow][sc + 4] = b1r;
    };

    loadAB(0); storeLDS(0);
    __syncthreads();

    float acc[2][2][4][4] = {};
    const int NT = CCHNK / 16;   // 32
    for (int t = 0; t < NT; ++t) {
        int cur = t & 1;
        if (t + 1 < NT) loadAB((t + 1) * 16);
#pragma unroll
        for (int k = 0; k < 16; ++k) {
            float4 a0 = *(const float4*)&As[cur][k][tm * 4];
            float4 a1 = *(const float4*)&As[cur][k][64 + tm * 4];
            float4 p0 = *(const float4*)&Bs[cur][k][tn * 4];
            float4 p1 = *(const float4*)&Bs[cur][k][64 + tn * 4];
            float av0[4] = {a0.x, a0.y, a0.z, a0.w};
            float av1[4] = {a1.x, a1.y, a1.z, a1.w};
            float bv0[4] = {p0.x, p0.y, p0.z, p0.w};
            float bv1[4] = {p1.x, p1.y, p1.z, p1.w};
#pragma unroll
            for (int i = 0; i < 4; ++i)
#pragma unroll
                for (int j = 0; j < 4; ++j) {
                    acc[0][0][i][j] = fmaf(av0[i], bv0[j], acc[0][0][i][j]);
                    acc[0][1][i][j] = fmaf(av0[i], bv1[j], acc[0][1][i][j]);
                    acc[1][0][i][j] = fmaf(av1[i], bv0[j], acc[1][0][i][j]);
                    acc[1][1][i][j] = fmaf(av1[i], bv1[j], acc[1][1][i][j]);
                }
        }
        if (t + 1 < NT) storeLDS(cur ^ 1);
        __syncthreads();
    }

    if (MODE == 0) {
#pragma unroll
        for (int ih = 0; ih < 2; ++ih)
#pragma unroll
        for (int i = 0; i < 4; ++i) {
            float* cp = corrT + ((size_t)b * HW + t0 + ih * 64 + tm * 4 + i) * HW + s0;
#pragma unroll
            for (int jh = 0; jh < 2; ++jh)
                *(float4*)(cp + jh * 64 + tn * 4) =
                    make_float4(acc[ih][jh][i][0], acc[ih][jh][i][1],
                                acc[ih][jh][i][2], acc[ih][jh][i][3]);
        }
        return;
    }
    // accumulate with previous chunks
#pragma unroll
    for (int ih = 0; ih < 2; ++ih)
#pragma unroll
    for (int i = 0; i < 4; ++i) {
        float* cp = corrT + ((size_t)b * HW + t0 + ih * 64 + tm * 4 + i) * HW + s0;
#pragma unroll
        for (int jh = 0; jh < 2; ++jh) {
            float4 o = *(const float4*)(cp + jh * 64 + tn * 4);
            acc[ih][jh][i][0] += o.x; acc[ih][jh][i][1] += o.y;
            acc[ih][jh][i][2] += o.z; acc[ih][jh][i][3] += o.w;
            if (MODE == 1)
                *(float4*)(cp + jh * 64 + tn * 4) =
                    make_float4(acc[ih][jh][i][0], acc[ih][jh][i][1],
                                acc[ih][jh][i][2], acc[ih][jh][i][3]);
        }
    }
    if (MODE == 1) return;

    // MODE 2: normalize + store + maxes
    float nt_[2][4], ns_[2][4];
#pragma unroll
    for (int ih = 0; ih < 2; ++ih)
#pragma unroll
    for (int i = 0; i < 4; ++i)
        nt_[ih][i] = 1.f / sqrtf(nrm_sq[(size_t)(4 + b) * HW + t0 + ih * 64 + tm * 4 + i] + 1e-6f);
#pragma unroll
    for (int jh = 0; jh < 2; ++jh)
#pragma unroll
    for (int j = 0; j < 4; ++j)
        ns_[jh][j] = 1.f / sqrtf(nrm_sq[(size_t)b * HW + s0 + jh * 64 + tn * 4 + j] + 1e-6f);

    float rowmax[2][4] = {};
    float colmax[2][4] = {};
#pragma unroll
    for (int ih = 0; ih < 2; ++ih)
#pragma unroll
    for (int i = 0; i < 4; ++i) {
        float* cp = corrT + ((size_t)b * HW + t0 + ih * 64 + tm * 4 + i) * HW + s0;
#pragma unroll
        for (int jh = 0; jh < 2; ++jh) {
#pragma unroll
            for (int j = 0; j < 4; ++j) {
                float v = acc[ih][jh][i][j] * nt_[ih][i] * ns_[jh][j];
                acc[ih][jh][i][j] = v;
                rowmax[ih][i] = fmaxf(rowmax[ih][i], v);
                colmax[jh][j] = fmaxf(colmax[jh][j], v);
            }
            *(float4*)(cp + jh * 64 + tn * 4) =
                make_float4(acc[ih][jh][i][0], acc[ih][jh][i][1],
                            acc[ih][jh][i][2], acc[ih][jh][i][3]);
        }
    }
    // tmax partials: reduce rowmax across the 16 tn lanes
#pragma unroll
    for (int off = 1; off <= 8; off <<= 1)
#pragma unroll
        for (int ih = 0; ih < 2; ++ih)
#pragma unroll
        for (int i = 0; i < 4; ++i)
            rowmax[ih][i] = fmaxf(rowmax[ih][i], __shfl_xor(rowmax[ih][i], off));
    if (tn == 0) {
#pragma unroll
        for (int ih = 0; ih < 2; ++ih)
#pragma unroll
        for (int i = 0; i < 4; ++i)
            tpar[((size_t)b * 8 + blockIdx.x) * HW + t0 + ih * 64 + tm * 4 + i] = rowmax[ih][i];
    }
    // smax partials: reduce colmax across tm via LDS
#pragma unroll
    for (int jh = 0; jh < 2; ++jh)
#pragma unroll
    for (int j = 0; j < 4; ++j)
        Bs[0][tm][jh * 64 + tn * 4 + j] = colmax[jh][j];
    __syncthreads();
    if (tid < 128) {
        float m = 0.f;
#pragma unroll
        for (int r = 0; r < 16; ++r) m = fmaxf(m, Bs[0][r][tid]);
        spar[((size_t)b * 8 + blockIdx.y) * HW + s0 + tid] = m;
    }
}

// ---------------------------------------------------------------------------
// Kernel 5: nrm_sq[img][p] = sum_mb nrm_parts[img][mb][p]  (4 m-blocks now)
// ---------------------------------------------------------------------------
__global__ void nrm_reduce(const float* __restrict__ nrm_parts, float* __restrict__ nrm_sq) {
    int img = blockIdx.y;
    int p = blockIdx.x * 256 + threadIdx.x;
    float s = 0.f;
#pragma unroll
    for (int mb = 0; mb < 4; ++mb)
        s += nrm_parts[((size_t)img * 4 + mb) * HW + p];
    nrm_sq[img * HW + p] = s;
}

// ---------------------------------------------------------------------------
// Kernel 6: combine smax/tmax partials (8 partials each)
// ---------------------------------------------------------------------------
__global__ void combine_max(const float* __restrict__ spar, const float* __restrict__ tpar,
                            float* __restrict__ smax, float* __restrict__ tmax) {
    int b = blockIdx.y;
    int i = blockIdx.x * 256 + threadIdx.x;
    float m = 0.f;
#pragma unroll
    for (int q = 0; q < 8; ++q) m = fmaxf(m, spar[((size_t)b * 8 + q) * HW + i]);
    smax[b * HW + i] = m;
    float m2 = 0.f;
#pragma unroll
    for (int q = 0; q < 8; ++q) m2 = fmaxf(m2, tpar[((size_t)b * 8 + q) * HW + i]);
    tmax[b * HW + i] = m2;
}

// ---------------------------------------------------------------------------
// Kernel 7: final — filter (x^3/(smax*tmax)) per tap row, separable bilinear,
// sharp softmax + soft-argmax -> flow.
// ---------------------------------------------------------------------------
__global__ __launch_bounds__(256) void final_kernel(const float* __restrict__ corrT,
                                                    const float* __restrict__ smax,
                                                    const float* __restrict__ tmax,
                                                    float* __restrict__ out) {
    __shared__ float vsh[1024];
    __shared__ float rbuf[16];
    int b = blockIdx.z;
    int typ = blockIdx.y;
    int txp = blockIdx.x;
    int tid = threadIdx.x;

    float fy = typ * (31.0f / 63.0f);
    int y0 = min((int)fy, 31); int y1 = min(y0 + 1, 31);
    float wy = fy - (float)y0;
    float fx = txp * (31.0f / 63.0f);
    int x0 = min((int)fx, 31); int x1 = min(x0 + 1, 31);
    float wx = fx - (float)x0;
    int tA = y0 * 32 + x0, tB = y0 * 32 + x1, tC = y1 * 32 + x0, tD = y1 * 32 + x1;
    const float* base = corrT + (size_t)b * HW * HW;
    const float* rA = base + (size_t)tA * HW;
    const float* rB = base + (size_t)tB * HW;
    const float* rC = base + (size_t)tC * HW;
    const float* rD = base + (size_t)tD * HW;
    float tmA_ = tmax[b * HW + tA]; if (tmA_ == 0.f) tmA_ = 1e-30f;
    float tmB_ = tmax[b * HW + tB]; if (tmB_ == 0.f) tmB_ = 1e-30f;
    float tmC_ = tmax[b * HW + tC]; if (tmC_ == 0.f) tmC_ = 1e-30f;
    float tmD_ = tmax[b * HW + tD]; if (tmD_ == 0.f) tmD_ = 1e-30f;
    float itA = 1.f / tmA_, itB = 1.f / tmB_, itC = 1.f / tmC_, itD = 1.f / tmD_;
    float wA = (1.f - wy) * (1.f - wx), wB = (1.f - wy) * wx;
    float wC = wy * (1.f - wx), wD = wy * wx;
#pragma unroll
    for (int u = 0; u < 4; ++u) {
        int s = u * 256 + tid;
        float sm = smax[b * HW + s]; if (sm == 0.f) sm = 1e-30f;
        float is = 1.f / sm;
        float a = rA[s]; a = a * a * a * is * itA;
        float b2 = rB[s]; b2 = b2 * b2 * b2 * is * itB;
        float c2 = rC[s]; c2 = c2 * c2 * c2 * is * itC;
        float d2 = rD[s]; d2 = d2 * d2 * d2 * is * itD;
        vsh[s] = wA * a + wB * b2 + wC * c2 + wD * d2;
    }
    __syncthreads();

    float cv[16];
    float lmax = -1e30f;
#pragma unroll
    for (int u = 0; u < 16; ++u) {
        int sp = u * 256 + tid;
        int i = sp >> 6, j = sp & 63;
        float gy = i * (31.0f / 63.0f);
        int sy0 = min((int)gy, 31); int sy1 = min(sy0 + 1, 31);
        float wyy = gy - (float)sy0;
        float gx = j * (31.0f / 63.0f);
        int sx0 = min((int)gx, 31); int sx1 = min(sx0 + 1, 31);
        float wxx = gx - (float)sx0;
        float v00 = vsh[sy0 * 32 + sx0], v01 = vsh[sy0 * 32 + sx1];
        float v10 = vsh[sy1 * 32 + sx0], v11 = vsh[sy1 * 32 + sx1];
        float c = (v00 * (1.f - wxx) + v01 * wxx) * (1.f - wyy)
                + (v10 * (1.f - wxx) + v11 * wxx) * wyy;
        cv[u] = c * 50.0f;
        lmax = fmaxf(lmax, cv[u]);
    }
#pragma unroll
    for (int off = 32; off >= 1; off >>= 1) lmax = fmaxf(lmax, __shfl_down(lmax, off));
    int lane = tid & 63, wv = tid >> 6;
    if (lane == 0) rbuf[wv] = lmax;
    __syncthreads();
    if (tid == 0) {
        float m = rbuf[0];
        for (int i = 1; i < 4; ++i) m = fmaxf(m, rbuf[i]);
        rbuf[0] = m;
    }
    __syncthreads();
    float m = rbuf[0];

    float e0 = 0.f, ex = 0.f, ey = 0.f;
#pragma unroll
    for (int u = 0; u < 16; ++u) {
        int sp = u * 256 + tid;
        int i = sp >> 6, j = sp & 63;
        float e = __expf(cv[u] - m);
        e0 += e;
        ex = fmaf(e, j * (2.0f / 63.0f) - 1.0f, ex);
        ey = fmaf(e, i * (2.0f / 63.0f) - 1.0f, ey);
    }
#pragma unroll
    for (int off = 32; off >= 1; off >>= 1) {
        e0 += __shfl_down(e0, off);
        ex += __shfl_down(ex, off);
        ey += __shfl_down(ey, off);
    }
    if (lane == 0) { rbuf[4 + wv] = e0; rbuf[8 + wv] = ex; rbuf[12 + wv] = ey; }
    __syncthreads();
    if (tid == 0) {
        float s0 = rbuf[4] + rbuf[5] + rbuf[6] + rbuf[7];
        float sx = rbuf[8] + rbuf[9] + rbuf[10] + rbuf[11];
        float sy = rbuf[12] + rbuf[13] + rbuf[14] + rbuf[15];
        float gx = sx / s0, gy = sy / s0;
        float mx = (gx + 1.f) * 31.5f;
        float my = (gy + 1.f) * 31.5f;
        out[(((size_t)b * 2 + 0) * 64 + typ) * 64 + txp] = mx - (float)txp;
        out[(((size_t)b * 2 + 1) * 64 + typ) * 64 + txp] = my - (float)typ;
    }
}

// ---------------------------------------------------------------------------
// Workspace (floats), total 8,773,632 = 33.47 MiB (proven layout):
//   corrT 4194304 | nrm_region 65536 (nrm_parts uses [0,32768), tpar [32768,65536))
//   nrm_sq 8192 | smax 4096 | spar 65536 (uses first 32768) | tmax 4096
//   pnorm 8192 | ctxbuf 229376 | chunkbuf 4194304
// No memset: every buffer is written before it is read.
// ---------------------------------------------------------------------------
extern "C" void kernel_launch(void* const* d_in, const int* in_sizes, int n_in,
                              void* d_out, int out_size, void* d_ws, size_t ws_size,
                              hipStream_t stream) {
    const float* src  = (const float*)d_in[0];
    const float* tgt  = (const float*)d_in[1];
    const float* sw   = (const float*)d_in[2];
    const float* sb   = (const float*)d_in[3];
    float* out = (float*)d_out;

    float* corrT      = (float*)d_ws;
    float* nrm_parts  = corrT + 4194304;
    float* tpar       = nrm_parts + 32768;
    float* nrm_sq     = nrm_parts + 65536;
    float* smax       = nrm_sq + 8192;
    float* spar       = smax + 4096;
    float* tmax       = spar + 65536;
    float* pnorm      = tmax + 4096;
    float* ctxbuf     = pnorm + 8192;
    float* chunkbuf   = ctxbuf + 229376;

    pnorm_kernel<<<dim3(8, 16), 64, 0, stream>>>(src, tgt, pnorm);
    ctx_kernel<<<dim3(8, 32), 896, 0, stream>>>(src, tgt, pnorm, ctxbuf);

    // chunk 0
    conv_chunk<true><<<dim3(8, 4, 8), 256, 0, stream>>>(src, tgt, ctxbuf, sw, sb,
                                                        chunkbuf, nrm_parts, 0);
    corr_chunk<0><<<dim3(8, 8, 4), 256, 0, stream>>>(chunkbuf, nrm_sq, corrT, spar, tpar);
    // chunks 1,2
    for (int c = 1; c < 3; ++c) {
        conv_chunk<false><<<dim3(8, 4, 8), 256, 0, stream>>>(src, tgt, ctxbuf, sw, sb,
                                                             chunkbuf, nrm_parts, c * CCHNK);
        corr_chunk<1><<<dim3(8, 8, 4), 256, 0, stream>>>(chunkbuf, nrm_sq, corrT, spar, tpar);
    }
    // chunk 3: conv, then finalize norms, then corr with fused normalize+maxes
    conv_chunk<false><<<dim3(8, 4, 8), 256, 0, stream>>>(src, tgt, ctxbuf, sw, sb,
                                                         chunkbuf, nrm_parts, 3 * CCHNK);
    nrm_reduce<<<dim3(4, 8), 256, 0, stream>>>(nrm_parts, nrm_sq);
    corr_chunk<2><<<dim3(8, 8, 4), 256, 0, stream>>>(chunkbuf, nrm_sq, corrT, spar, tpar);

    combine_max<<<dim3(4, 4), 256, 0, stream>>>(spar, tpar, smax, tmax);
    final_kernel<<<dim3(64, 64, 4), 256, 0, stream>>>(corrT, smax, tmax, out);
}

// Round 6
// 598.357 us; speedup vs baseline: 2.1505x; 2.1505x over previous
//
#include <hip/hip_runtime.h>
#include <math.h>

#define HW    1024
#define CIN   1024
#define CCTX  28
#define CALL  1052
#define COUT  2048
#define CCHNK 512

typedef _Float16 half8   __attribute__((ext_vector_type(8)));
typedef _Float16 half4_t __attribute__((ext_vector_type(4)));
typedef float    f32x4   __attribute__((ext_vector_type(4)));

__device__ __forceinline__ void split_f16(float x, _Float16& h, _Float16& l) {
    _Float16 hh = (_Float16)x;
    h = hh;
    l = (_Float16)(x - (float)hh);
}
__device__ __forceinline__ float f4get(const float4& v, int e) {
    return e == 0 ? v.x : e == 1 ? v.y : e == 2 ? v.z : v.w;
}

// ---------------------------------------------------------------------------
// Kernel 1: per-pixel feature L2 norm (unchanged, proven)
// ---------------------------------------------------------------------------
__global__ void pnorm_kernel(const float* __restrict__ src, const float* __restrict__ tgt,
                             float* __restrict__ pnorm) {
    int img = blockIdx.x;
    int p = blockIdx.y * 64 + threadIdx.x;
    const float* feat = (img < 4) ? src + (size_t)img * CIN * HW
                                  : tgt + (size_t)(img - 4) * CIN * HW;
    float ss = 0.f;
    for (int c = 0; c < CIN; ++c) {
        float v = feat[(size_t)c * HW + p];
        ss = fmaf(v, v, ss);
    }
    pnorm[img * HW + p] = fmaxf(sqrtf(ss), 1e-12f);
}

// ---------------------------------------------------------------------------
// Kernel 2: shifted local correlations (unchanged, proven)
// ---------------------------------------------------------------------------
__global__ void ctx_kernel(const float* __restrict__ src, const float* __restrict__ tgt,
                           const float* __restrict__ pnorm, float* __restrict__ ctx) {
    int img = blockIdx.x;
    int y = blockIdx.y;
    int tid = threadIdx.x;
    int o = tid >> 5;
    int x = tid & 31;
    const float* feat = (img < 4) ? src + (size_t)img * CIN * HW
                                  : tgt + (size_t)(img - 4) * CIN * HW;
    int g = o / 7, i = o % 7;
    int r, c;
    if (g == 0)      { r = i; c = i; }
    else if (g == 1) { r = i; c = 3; }
    else if (g == 2) { r = i; c = 6 - i; }
    else             { r = 3; c = i; }
    int y2 = y + r - 3, x2 = x + c - 3;
    int p = y * 32 + x;
    float outv = 0.f;
    if (y2 >= 0 && y2 < 32 && x2 >= 0 && x2 < 32) {
        int p2 = y2 * 32 + x2;
        const float* f0 = feat + p;
        const float* f1 = feat + p2;
        float acc = 0.f;
        for (int ch = 0; ch < CIN; ++ch)
            acc = fmaf(f0[(size_t)ch * HW], f1[(size_t)ch * HW], acc);
        outv = acc / (pnorm[img * HW + p] * pnorm[img * HW + p2]);
    }
    ctx[((size_t)img * CCTX + o) * HW + p] = outv;
}

// ---------------------------------------------------------------------------
// Kernel 3: conv via MFMA, D = X^T (pix=M 64) x W^T (chan=N 128), K=1052.
// f16 hi/lo 3-term split at staging; output Y[img][pix][chan-chunk] fp32.
// grid (4 chan-blk, 16 pix-blk, 8 img) = 512 blocks, 256 threads (4 waves 2x2).
// ---------------------------------------------------------------------------
template <bool FIRST>
__global__ __launch_bounds__(256, 2) void conv_mfma(
    const float* __restrict__ src, const float* __restrict__ tgt,
    const float* __restrict__ ctxb, const float* __restrict__ w,
    const float* __restrict__ bias, float* __restrict__ ychunk,
    float* __restrict__ nrm_parts, int c0) {
    __shared__ __align__(16) char smem[55296];
    _Float16* Ah = (_Float16*)smem;          // [64][72]  pix x k
    _Float16* Al = Ah + 64 * 72;
    _Float16* Bh = Al + 64 * 72;             // [128][72] chan x k
    _Float16* Bl = Bh + 128 * 72;

    int cb = blockIdx.x;
    int pb = blockIdx.y;
    int img = blockIdx.z;
    int n0 = pb * 64;
    int m0g = c0 + cb * 128;
    const float* feat = (img < 4) ? src + (size_t)img * CIN * HW
                                  : tgt + (size_t)(img - 4) * CIN * HW;
    const float* ctxi = ctxb + (size_t)img * CCTX * HW;
    int tid = threadIdx.x;

    int aq = tid & 15, ar = tid >> 4;        // A: pixel-quad, k-quad
    int brow = tid >> 1, bh_ = tid & 1;      // B: chan row, k-half

    float4 xa[4], xb[8];
    auto loadA = [&](int k0) {
#pragma unroll
        for (int j = 0; j < 4; ++j) {
            int k = k0 + ar * 4 + j;
            if (k < CIN)       xa[j] = *(const float4*)(feat + (size_t)k * HW + n0 + aq * 4);
            else if (k < CALL) xa[j] = *(const float4*)(ctxi + (size_t)(k - CIN) * HW + n0 + aq * 4);
            else               xa[j] = make_float4(0.f, 0.f, 0.f, 0.f);
        }
    };
    auto loadB = [&](int k0) {
#pragma unroll
        for (int i = 0; i < 8; ++i) {
            int k = k0 + bh_ * 32 + i * 4;
            xb[i] = (k < CALL) ? *(const float4*)(w + (size_t)(m0g + brow) * CALL + k)
                               : make_float4(0.f, 0.f, 0.f, 0.f);
        }
    };
    auto storeLDS = [&]() {
        // A: 4x4 in-register transpose -> [pix][k]
#pragma unroll
        for (int p = 0; p < 4; ++p) {
            half4_t h, l;
#pragma unroll
            for (int j = 0; j < 4; ++j) {
                _Float16 hh, ll; split_f16(f4get(xa[j], p), hh, ll);
                h[j] = hh; l[j] = ll;
            }
            int row = aq * 4 + p;
            *(half4_t*)(Ah + row * 72 + ar * 4) = h;
            *(half4_t*)(Al + row * 72 + ar * 4) = l;
        }
        // B: straight [chan][k]
#pragma unroll
        for (int g = 0; g < 4; ++g) {
            half8 h, l;
#pragma unroll
            for (int e = 0; e < 8; ++e) {
                _Float16 hh, ll; split_f16(f4get(xb[g * 2 + (e >> 2)], e & 3), hh, ll);
                h[e] = hh; l[e] = ll;
            }
            *(half8*)(Bh + brow * 72 + bh_ * 32 + g * 8) = h;
            *(half8*)(Bl + brow * 72 + bh_ * 32 + g * 8) = l;
        }
    };

    int lane = tid & 63, wv = tid >> 6;
    int wm = wv >> 1, wn = wv & 1;
    int frow = lane & 15;
    int kcol = (lane >> 4) * 8;

    f32x4 acc[2][4] = {};
    const int NT = 17;   // ceil(1052/64)
    loadA(0); loadB(0); storeLDS();
    __syncthreads();
    for (int s = 0; s < NT; ++s) {
        if (s + 1 < NT) { loadA((s + 1) * 64); loadB((s + 1) * 64); }
#pragma unroll
        for (int ks = 0; ks < 2; ++ks) {
            int ko = ks * 32 + kcol;
            half8 ah[2], al_[2], bhv[4], blv[4];
#pragma unroll
            for (int fm = 0; fm < 2; ++fm) {
                int r = wm * 32 + fm * 16 + frow;
                ah[fm]  = *(const half8*)(Ah + r * 72 + ko);
                al_[fm] = *(const half8*)(Al + r * 72 + ko);
            }
#pragma unroll
            for (int fn = 0; fn < 4; ++fn) {
                int r = wn * 64 + fn * 16 + frow;
                bhv[fn] = *(const half8*)(Bh + r * 72 + ko);
                blv[fn] = *(const half8*)(Bl + r * 72 + ko);
            }
#pragma unroll
            for (int fm = 0; fm < 2; ++fm)
#pragma unroll
                for (int fn = 0; fn < 4; ++fn) {
                    acc[fm][fn] = __builtin_amdgcn_mfma_f32_16x16x32_f16(ah[fm],  bhv[fn], acc[fm][fn], 0, 0, 0);
                    acc[fm][fn] = __builtin_amdgcn_mfma_f32_16x16x32_f16(ah[fm],  blv[fn], acc[fm][fn], 0, 0, 0);
                    acc[fm][fn] = __builtin_amdgcn_mfma_f32_16x16x32_f16(al_[fm], bhv[fn], acc[fm][fn], 0, 0, 0);
                }
        }
        __syncthreads();
        if (s + 1 < NT) { storeLDS(); __syncthreads(); }
    }

    // epilogue: bias+relu, bounce via LDS to coalesced Y store, nrm partials
    float* ybounce = (float*)smem;           // [64][132]
    float* ns = ybounce + 64 * 132;          // [2][64]
    float psum[2][4] = {};
#pragma unroll
    for (int fm = 0; fm < 2; ++fm)
#pragma unroll
        for (int fn = 0; fn < 4; ++fn) {
            int chan_l = wn * 64 + fn * 16 + (lane & 15);
            float bv = bias[m0g + chan_l];
#pragma unroll
            for (int r = 0; r < 4; ++r) {
                float v = fmaxf(acc[fm][fn][r] + bv, 0.f);
                int pix_l = wm * 32 + fm * 16 + (lane >> 4) * 4 + r;
                ybounce[pix_l * 132 + chan_l] = v;
                psum[fm][r] = fmaf(v, v, psum[fm][r]);
            }
        }
#pragma unroll
    for (int off = 1; off <= 8; off <<= 1)
#pragma unroll
        for (int fm = 0; fm < 2; ++fm)
#pragma unroll
            for (int r = 0; r < 4; ++r)
                psum[fm][r] = psum[fm][r] + __shfl_xor(psum[fm][r], off);
    if ((lane & 15) == 0) {
#pragma unroll
        for (int fm = 0; fm < 2; ++fm)
#pragma unroll
            for (int r = 0; r < 4; ++r)
                ns[wn * 64 + wm * 32 + fm * 16 + (lane >> 4) * 4 + r] = psum[fm][r];
    }
    __syncthreads();
    {
        int row = tid >> 2, seg = tid & 3;
        float* yp = ychunk + ((size_t)img * HW + n0 + row) * CCHNK + cb * 128 + seg * 32;
#pragma unroll
        for (int i = 0; i < 8; ++i)
            *(float4*)(yp + i * 4) = *(float4*)(ybounce + row * 132 + seg * 32 + i * 4);
    }
    if (tid < 64) {
        float sv = ns[tid] + ns[64 + tid];
        float* np = nrm_parts + ((size_t)img * 4 + cb) * HW + n0 + tid;
        if (FIRST) *np = sv; else *np += sv;
    }
}

// ---------------------------------------------------------------------------
// Kernel 4: correlation via MFMA, tile t=64(M) x s=128(N), K=512 per chunk.
// Both operands from Y [pix][chan] fp32, k-contiguous (no transpose).
// MODE 0: store; 1: accumulate; 2: accumulate+normalize+max partials.
// grid (8 s-blk, 16 t-blk, 4 b) = 512 blocks.
// ---------------------------------------------------------------------------
template <int MODE>
__global__ __launch_bounds__(256, 2) void corr_mfma(
    const float* __restrict__ ychunk, const float* __restrict__ nrm_sq,
    float* __restrict__ corrT, float* __restrict__ spar, float* __restrict__ tpar) {
    __shared__ __align__(16) char smem[55296];
    _Float16* Ah = (_Float16*)smem;
    _Float16* Al = Ah + 64 * 72;
    _Float16* Bh = Al + 64 * 72;
    _Float16* Bl = Bh + 128 * 72;

    int sb = blockIdx.x, tb = blockIdx.y, b = blockIdx.z;
    int t0 = tb * 64, s0 = sb * 128;
    const float* ytg = ychunk + (size_t)(4 + b) * HW * CCHNK;
    const float* ysr = ychunk + (size_t)b * HW * CCHNK;
    int tid = threadIdx.x;
    int arow = tid >> 2, akq = tid & 3;
    int brow = tid >> 1, bh_ = tid & 1;

    float4 xa[4], xb[8];
    auto loadA = [&](int k0) {
#pragma unroll
        for (int i = 0; i < 4; ++i)
            xa[i] = *(const float4*)(ytg + (size_t)(t0 + arow) * CCHNK + k0 + akq * 16 + i * 4);
    };
    auto loadB = [&](int k0) {
#pragma unroll
        for (int i = 0; i < 8; ++i)
            xb[i] = *(const float4*)(ysr + (size_t)(s0 + brow) * CCHNK + k0 + bh_ * 32 + i * 4);
    };
    auto storeLDS = [&]() {
#pragma unroll
        for (int g = 0; g < 2; ++g) {
            half8 h, l;
#pragma unroll
            for (int e = 0; e < 8; ++e) {
                _Float16 hh, ll; split_f16(f4get(xa[g * 2 + (e >> 2)], e & 3), hh, ll);
                h[e] = hh; l[e] = ll;
            }
            *(half8*)(Ah + arow * 72 + akq * 16 + g * 8) = h;
            *(half8*)(Al + arow * 72 + akq * 16 + g * 8) = l;
        }
#pragma unroll
        for (int g = 0; g < 4; ++g) {
            half8 h, l;
#pragma unroll
            for (int e = 0; e < 8; ++e) {
                _Float16 hh, ll; split_f16(f4get(xb[g * 2 + (e >> 2)], e & 3), hh, ll);
                h[e] = hh; l[e] = ll;
            }
            *(half8*)(Bh + brow * 72 + bh_ * 32 + g * 8) = h;
            *(half8*)(Bl + brow * 72 + bh_ * 32 + g * 8) = l;
        }
    };

    int lane = tid & 63, wv = tid >> 6;
    int wm = wv >> 1, wn = wv & 1;
    int frow = lane & 15;
    int kcol = (lane >> 4) * 8;

    f32x4 acc[2][4] = {};
    const int NT = CCHNK / 64;   // 8
    loadA(0); loadB(0); storeLDS();
    __syncthreads();
    for (int s = 0; s < NT; ++s) {
        if (s + 1 < NT) { loadA((s + 1) * 64); loadB((s + 1) * 64); }
#pragma unroll
        for (int ks = 0; ks < 2; ++ks) {
            int ko = ks * 32 + kcol;
            half8 ah[2], al_[2], bhv[4], blv[4];
#pragma unroll
            for (int fm = 0; fm < 2; ++fm) {
                int r = wm * 32 + fm * 16 + frow;
                ah[fm]  = *(const half8*)(Ah + r * 72 + ko);
                al_[fm] = *(const half8*)(Al + r * 72 + ko);
            }
#pragma unroll
            for (int fn = 0; fn < 4; ++fn) {
                int r = wn * 64 + fn * 16 + frow;
                bhv[fn] = *(const half8*)(Bh + r * 72 + ko);
                blv[fn] = *(const half8*)(Bl + r * 72 + ko);
            }
#pragma unroll
            for (int fm = 0; fm < 2; ++fm)
#pragma unroll
                for (int fn = 0; fn < 4; ++fn) {
                    acc[fm][fn] = __builtin_amdgcn_mfma_f32_16x16x32_f16(ah[fm],  bhv[fn], acc[fm][fn], 0, 0, 0);
                    acc[fm][fn] = __builtin_amdgcn_mfma_f32_16x16x32_f16(ah[fm],  blv[fn], acc[fm][fn], 0, 0, 0);
                    acc[fm][fn] = __builtin_amdgcn_mfma_f32_16x16x32_f16(al_[fm], bhv[fn], acc[fm][fn], 0, 0, 0);
                }
        }
        __syncthreads();
        if (s + 1 < NT) { storeLDS(); __syncthreads(); }
    }

    float rnt[2][4], rns[4];
    float rowmax[2][4] = {};
    float colmax[4] = {};
    if (MODE == 2) {
#pragma unroll
        for (int fm = 0; fm < 2; ++fm)
#pragma unroll
            for (int r = 0; r < 4; ++r) {
                int t = t0 + wm * 32 + fm * 16 + (lane >> 4) * 4 + r;
                rnt[fm][r] = 1.f / sqrtf(nrm_sq[(size_t)(4 + b) * HW + t] + 1e-6f);
            }
#pragma unroll
        for (int fn = 0; fn < 4; ++fn) {
            int s_ = s0 + wn * 64 + fn * 16 + (lane & 15);
            rns[fn] = 1.f / sqrtf(nrm_sq[(size_t)b * HW + s_] + 1e-6f);
        }
    }
#pragma unroll
    for (int fm = 0; fm < 2; ++fm)
#pragma unroll
        for (int r = 0; r < 4; ++r) {
            int t = t0 + wm * 32 + fm * 16 + (lane >> 4) * 4 + r;
            float* cp = corrT + ((size_t)b * HW + t) * HW + s0 + wn * 64 + (lane & 15);
#pragma unroll
            for (int fn = 0; fn < 4; ++fn) {
                float v = acc[fm][fn][r];
                if (MODE >= 1) v += cp[fn * 16];
                if (MODE == 2) {
                    v *= rnt[fm][r] * rns[fn];
                    rowmax[fm][r] = fmaxf(rowmax[fm][r], v);
                    colmax[fn] = fmaxf(colmax[fn], v);
                }
                cp[fn * 16] = v;
            }
        }
    if (MODE == 2) {
        float* rm = (float*)smem;        // [2][64] per-wn t-row maxes
        float* cm = rm + 128;            // [4 waves][64] per-wave s-col maxes
#pragma unroll
        for (int off = 1; off <= 8; off <<= 1)
#pragma unroll
            for (int fm = 0; fm < 2; ++fm)
#pragma unroll
                for (int r = 0; r < 4; ++r)
                    rowmax[fm][r] = fmaxf(rowmax[fm][r], __shfl_xor(rowmax[fm][r], off));
        if ((lane & 15) == 0) {
#pragma unroll
            for (int fm = 0; fm < 2; ++fm)
#pragma unroll
                for (int r = 0; r < 4; ++r)
                    rm[wn * 64 + wm * 32 + fm * 16 + (lane >> 4) * 4 + r] = rowmax[fm][r];
        }
#pragma unroll
        for (int off = 16; off <= 32; off <<= 1)
#pragma unroll
            for (int fn = 0; fn < 4; ++fn)
                colmax[fn] = fmaxf(colmax[fn], __shfl_xor(colmax[fn], off));
        if ((lane >> 4) == 0) {
#pragma unroll
            for (int fn = 0; fn < 4; ++fn)
                cm[wv * 64 + fn * 16 + (lane & 15)] = colmax[fn];
        }
        __syncthreads();
        if (tid < 64)
            tpar[((size_t)b * 8 + sb) * HW + t0 + tid] = fmaxf(rm[tid], rm[64 + tid]);
        if (tid < 128) {
            int q = tid >> 6;   // wn half
            float mv = fmaxf(cm[q * 64 + (tid & 63)], cm[(2 + q) * 64 + (tid & 63)]);
            spar[((size_t)b * 16 + tb) * HW + s0 + tid] = mv;
        }
    }
}

// ---------------------------------------------------------------------------
// Kernel 5: nrm_sq[img][p] = sum of 4 chan-block partials
// ---------------------------------------------------------------------------
__global__ void nrm_reduce(const float* __restrict__ nrm_parts, float* __restrict__ nrm_sq) {
    int img = blockIdx.y;
    int p = blockIdx.x * 256 + threadIdx.x;
    float s = 0.f;
#pragma unroll
    for (int mb = 0; mb < 4; ++mb)
        s += nrm_parts[((size_t)img * 4 + mb) * HW + p];
    nrm_sq[img * HW + p] = s;
}

// ---------------------------------------------------------------------------
// Kernel 6: combine smax (16 t-block partials) / tmax (8 s-block partials)
// ---------------------------------------------------------------------------
__global__ void combine_max(const float* __restrict__ spar, const float* __restrict__ tpar,
                            float* __restrict__ smax, float* __restrict__ tmax) {
    int b = blockIdx.y;
    int i = blockIdx.x * 256 + threadIdx.x;
    float m = 0.f;
#pragma unroll
    for (int q = 0; q < 16; ++q) m = fmaxf(m, spar[((size_t)b * 16 + q) * HW + i]);
    smax[b * HW + i] = m;
    float m2 = 0.f;
#pragma unroll
    for (int q = 0; q < 8; ++q) m2 = fmaxf(m2, tpar[((size_t)b * 8 + q) * HW + i]);
    tmax[b * HW + i] = m2;
}

// ---------------------------------------------------------------------------
// Kernel 7: final (unchanged, proven) — filter x^3/(smax*tmax) per tap row,
// separable bilinear, sharp softmax + soft-argmax -> flow.
// ---------------------------------------------------------------------------
__global__ __launch_bounds__(256) void final_kernel(const float* __restrict__ corrT,
                                                    const float* __restrict__ smax,
                                                    const float* __restrict__ tmax,
                                                    float* __restrict__ out) {
    __shared__ float vsh[1024];
    __shared__ float rbuf[16];
    int b = blockIdx.z;
    int typ = blockIdx.y;
    int txp = blockIdx.x;
    int tid = threadIdx.x;

    float fy = typ * (31.0f / 63.0f);
    int y0 = min((int)fy, 31); int y1 = min(y0 + 1, 31);
    float wy = fy - (float)y0;
    float fx = txp * (31.0f / 63.0f);
    int x0 = min((int)fx, 31); int x1 = min(x0 + 1, 31);
    float wx = fx - (float)x0;
    int tA = y0 * 32 + x0, tB = y0 * 32 + x1, tC = y1 * 32 + x0, tD = y1 * 32 + x1;
    const float* base = corrT + (size_t)b * HW * HW;
    const float* rA = base + (size_t)tA * HW;
    const float* rB = base + (size_t)tB * HW;
    const float* rC = base + (size_t)tC * HW;
    const float* rD = base + (size_t)tD * HW;
    float tmA_ = tmax[b * HW + tA]; if (tmA_ == 0.f) tmA_ = 1e-30f;
    float tmB_ = tmax[b * HW + tB]; if (tmB_ == 0.f) tmB_ = 1e-30f;
    float tmC_ = tmax[b * HW + tC]; if (tmC_ == 0.f) tmC_ = 1e-30f;
    float tmD_ = tmax[b * HW + tD]; if (tmD_ == 0.f) tmD_ = 1e-30f;
    float itA = 1.f / tmA_, itB = 1.f / tmB_, itC = 1.f / tmC_, itD = 1.f / tmD_;
    float wA = (1.f - wy) * (1.f - wx), wB = (1.f - wy) * wx;
    float wC = wy * (1.f - wx), wD = wy * wx;
#pragma unroll
    for (int u = 0; u < 4; ++u) {
        int s = u * 256 + tid;
        float sm = smax[b * HW + s]; if (sm == 0.f) sm = 1e-30f;
        float is = 1.f / sm;
        float a = rA[s]; a = a * a * a * is * itA;
        float b2 = rB[s]; b2 = b2 * b2 * b2 * is * itB;
        float c2 = rC[s]; c2 = c2 * c2 * c2 * is * itC;
        float d2 = rD[s]; d2 = d2 * d2 * d2 * is * itD;
        vsh[s] = wA * a + wB * b2 + wC * c2 + wD * d2;
    }
    __syncthreads();

    float cv[16];
    float lmax = -1e30f;
#pragma unroll
    for (int u = 0; u < 16; ++u) {
        int sp = u * 256 + tid;
        int i = sp >> 6, j = sp & 63;
        float gy = i * (31.0f / 63.0f);
        int sy0 = min((int)gy, 31); int sy1 = min(sy0 + 1, 31);
        float wyy = gy - (float)sy0;
        float gx = j * (31.0f / 63.0f);
        int sx0 = min((int)gx, 31); int sx1 = min(sx0 + 1, 31);
        float wxx = gx - (float)sx0;
        float v00 = vsh[sy0 * 32 + sx0], v01 = vsh[sy0 * 32 + sx1];
        float v10 = vsh[sy1 * 32 + sx0], v11 = vsh[sy1 * 32 + sx1];
        float c = (v00 * (1.f - wxx) + v01 * wxx) * (1.f - wyy)
                + (v10 * (1.f - wxx) + v11 * wxx) * wyy;
        cv[u] = c * 50.0f;
        lmax = fmaxf(lmax, cv[u]);
    }
#pragma unroll
    for (int off = 32; off >= 1; off >>= 1) lmax = fmaxf(lmax, __shfl_down(lmax, off));
    int lane = tid & 63, wv = tid >> 6;
    if (lane == 0) rbuf[wv] = lmax;
    __syncthreads();
    if (tid == 0) {
        float m = rbuf[0];
        for (int i = 1; i < 4; ++i) m = fmaxf(m, rbuf[i]);
        rbuf[0] = m;
    }
    __syncthreads();
    float m = rbuf[0];

    float e0 = 0.f, ex = 0.f, ey = 0.f;
#pragma unroll
    for (int u = 0; u < 16; ++u) {
        int sp = u * 256 + tid;
        int i = sp >> 6, j = sp & 63;
        float e = __expf(cv[u] - m);
        e0 += e;
        ex = fmaf(e, j * (2.0f / 63.0f) - 1.0f, ex);
        ey = fmaf(e, i * (2.0f / 63.0f) - 1.0f, ey);
    }
#pragma unroll
    for (int off = 32; off >= 1; off >>= 1) {
        e0 += __shfl_down(e0, off);
        ex += __shfl_down(ex, off);
        ey += __shfl_down(ey, off);
    }
    if (lane == 0) { rbuf[4 + wv] = e0; rbuf[8 + wv] = ex; rbuf[12 + wv] = ey; }
    __syncthreads();
    if (tid == 0) {
        float s0 = rbuf[4] + rbuf[5] + rbuf[6] + rbuf[7];
        float sx = rbuf[8] + rbuf[9] + rbuf[10] + rbuf[11];
        float sy = rbuf[12] + rbuf[13] + rbuf[14] + rbuf[15];
        float gx = sx / s0, gy = sy / s0;
        float mx = (gx + 1.f) * 31.5f;
        float my = (gy + 1.f) * 31.5f;
        out[(((size_t)b * 2 + 0) * 64 + typ) * 64 + txp] = mx - (float)txp;
        out[(((size_t)b * 2 + 1) * 64 + typ) * 64 + txp] = my - (float)typ;
    }
}

// ---------------------------------------------------------------------------
// Workspace (floats), total 8,773,632 = 33.47 MiB — IDENTICAL to proven layout.
//   corrT 4194304 | nrm_parts 32768 | tpar 32768 | nrm_sq 8192 | smax 4096
//   spar 65536 | tmax 4096 | pnorm 8192 | ctxbuf 229376 | ychunk 4194304
// No memset: every buffer written before read.
// ---------------------------------------------------------------------------
extern "C" void kernel_launch(void* const* d_in, const int* in_sizes, int n_in,
                              void* d_out, int out_size, void* d_ws, size_t ws_size,
                              hipStream_t stream) {
    const float* src  = (const float*)d_in[0];
    const float* tgt  = (const float*)d_in[1];
    const float* sw   = (const float*)d_in[2];
    const float* sb   = (const float*)d_in[3];
    float* out = (float*)d_out;

    float* corrT      = (float*)d_ws;
    float* nrm_parts  = corrT + 4194304;
    float* tpar       = nrm_parts + 32768;
    float* nrm_sq     = nrm_parts + 65536;
    float* smax       = nrm_sq + 8192;
    float* spar       = smax + 4096;
    float* tmax       = spar + 65536;
    float* pnorm      = tmax + 4096;
    float* ctxbuf     = pnorm + 8192;
    float* ychunk     = ctxbuf + 229376;

    pnorm_kernel<<<dim3(8, 16), 64, 0, stream>>>(src, tgt, pnorm);
    ctx_kernel<<<dim3(8, 32), 896, 0, stream>>>(src, tgt, pnorm, ctxbuf);

    // chunk 0
    conv_mfma<true><<<dim3(4, 16, 8), 256, 0, stream>>>(src, tgt, ctxbuf, sw, sb,
                                                        ychunk, nrm_parts, 0);
    corr_mfma<0><<<dim3(8, 16, 4), 256, 0, stream>>>(ychunk, nrm_sq, corrT, spar, tpar);
    // chunks 1,2
    for (int c = 1; c < 3; ++c) {
        conv_mfma<false><<<dim3(4, 16, 8), 256, 0, stream>>>(src, tgt, ctxbuf, sw, sb,
                                                             ychunk, nrm_parts, c * CCHNK);
        corr_mfma<1><<<dim3(8, 16, 4), 256, 0, stream>>>(ychunk, nrm_sq, corrT, spar, tpar);
    }
    // chunk 3: conv, finalize norms, corr with fused normalize+maxes
    conv_mfma<false><<<dim3(4, 16, 8), 256, 0, stream>>>(src, tgt, ctxbuf, sw, sb,
                                                         ychunk, nrm_parts, 3 * CCHNK);
    nrm_reduce<<<dim3(4, 8), 256, 0, stream>>>(nrm_parts, nrm_sq);
    corr_mfma<2><<<dim3(8, 16, 4), 256, 0, stream>>>(ychunk, nrm_sq, corrT, spar, tpar);

    combine_max<<<dim3(4, 4), 256, 0, stream>>>(spar, tpar, smax, tmax);
    final_kernel<<<dim3(64, 64, 4), 256, 0, stream>>>(corrT, smax, tmax, out);
}

// Round 8
// 531.268 us; speedup vs baseline: 2.4221x; 1.1263x over previous
//
#include <hip/hip_runtime.h>
#include <math.h>

#define HW    1024
#define CIN   1024
#define CCTX  28
#define CALL  1052
#define COUT  2048
#define CCHNK 512

typedef _Float16 half8   __attribute__((ext_vector_type(8)));
typedef _Float16 half4_t __attribute__((ext_vector_type(4)));
typedef _Float16 half2_t __attribute__((ext_vector_type(2)));
typedef __fp16   fp16x2  __attribute__((ext_vector_type(2)));
typedef float    f32x4   __attribute__((ext_vector_type(4)));

// split a into hi (exact top-10-bit mantissa, fits f16) + lo, packed pairwise.
__device__ __forceinline__ void split2(float a0, float a1, half2_t& h, half2_t& l) {
    float h0 = __uint_as_float(__float_as_uint(a0) & 0xFFFFE000u);
    float h1 = __uint_as_float(__float_as_uint(a1) & 0xFFFFE000u);
    fp16x2 hp = __builtin_amdgcn_cvt_pkrtz(h0, h1);           // exact
    fp16x2 lp = __builtin_amdgcn_cvt_pkrtz(a0 - h0, a1 - h1);
    h = __builtin_bit_cast(half2_t, hp);
    l = __builtin_bit_cast(half2_t, lp);
}
__device__ __forceinline__ void split4(float4 v, half4_t& h, half4_t& l) {
    half2_t ha, la, hb, lb;
    split2(v.x, v.y, ha, la);
    split2(v.z, v.w, hb, lb);
    h = __builtin_shufflevector(ha, hb, 0, 1, 2, 3);
    l = __builtin_shufflevector(la, lb, 0, 1, 2, 3);
}
__device__ __forceinline__ float f4get(const float4& v, int e) {
    return e == 0 ? v.x : e == 1 ? v.y : e == 2 ? v.z : v.w;
}

// ---------------------------------------------------------------------------
// Kernel 1a: pnorm partials — 4 channel-quarters per pixel (ILP + parallelism)
// grid (8 img, 16 pixblk, 4 part), block 64. parts aliases ychunk (dead).
// ---------------------------------------------------------------------------
__global__ void pnorm_part(const float* __restrict__ src, const float* __restrict__ tgt,
                           float* __restrict__ parts) {
    int img = blockIdx.x, pb = blockIdx.y, part = blockIdx.z;
    int p = pb * 64 + threadIdx.x;
    const float* feat = ((img < 4) ? src + (size_t)img * CIN * HW
                                   : tgt + (size_t)(img - 4) * CIN * HW)
                        + (size_t)part * 256 * HW + p;
    float a4[4] = {};
    for (int c = 0; c < 256; c += 8) {
        float v[8];
#pragma unroll
        for (int j = 0; j < 8; ++j) v[j] = feat[(size_t)(c + j) * HW];
#pragma unroll
        for (int j = 0; j < 8; ++j) a4[j & 3] = fmaf(v[j], v[j], a4[j & 3]);
    }
    parts[(size_t)part * 8192 + img * 1024 + p] = (a4[0] + a4[1]) + (a4[2] + a4[3]);
}
__global__ void pnorm_combine(const float* __restrict__ parts, float* __restrict__ pnorm) {
    int img = blockIdx.x;
    int p = blockIdx.y * 64 + threadIdx.x;
    float s = parts[img * 1024 + p] + parts[8192 + img * 1024 + p]
            + parts[16384 + img * 1024 + p] + parts[24576 + img * 1024 + p];
    pnorm[img * HW + p] = fmaxf(sqrtf(s), 1e-12f);
}

// ---------------------------------------------------------------------------
// Kernel 2: shifted local correlations, unroll-8 for load ILP
// ---------------------------------------------------------------------------
__global__ void ctx_kernel(const float* __restrict__ src, const float* __restrict__ tgt,
                           const float* __restrict__ pnorm, float* __restrict__ ctx) {
    int img = blockIdx.x;
    int y = blockIdx.y;
    int tid = threadIdx.x;
    int o = tid >> 5;
    int x = tid & 31;
    const float* feat = (img < 4) ? src + (size_t)img * CIN * HW
                                  : tgt + (size_t)(img - 4) * CIN * HW;
    int g = o / 7, i = o % 7;
    int r, c;
    if (g == 0)      { r = i; c = i; }
    else if (g == 1) { r = i; c = 3; }
    else if (g == 2) { r = i; c = 6 - i; }
    else             { r = 3; c = i; }
    int y2 = y + r - 3, x2 = x + c - 3;
    int p = y * 32 + x;
    float outv = 0.f;
    if (y2 >= 0 && y2 < 32 && x2 >= 0 && x2 < 32) {
        int p2 = y2 * 32 + x2;
        const float* f0 = feat + p;
        const float* f1 = feat + p2;
        float a4[4] = {};
        for (int ch = 0; ch < CIN; ch += 8) {
            float va[8], vb[8];
#pragma unroll
            for (int j = 0; j < 8; ++j) {
                va[j] = f0[(size_t)(ch + j) * HW];
                vb[j] = f1[(size_t)(ch + j) * HW];
            }
#pragma unroll
            for (int j = 0; j < 8; ++j) a4[j & 3] = fmaf(va[j], vb[j], a4[j & 3]);
        }
        float acc = (a4[0] + a4[1]) + (a4[2] + a4[3]);
        outv = acc / (pnorm[img * HW + p] * pnorm[img * HW + p2]);
    }
    ctx[((size_t)img * CCTX + o) * HW + p] = outv;
}

// ---------------------------------------------------------------------------
// Kernel 3: conv via MFMA, tile pix=64(M) x chan=128(N), BK=32, dbuf LDS,
// one barrier per tile. grid (4 chan-blk, 16 pix-blk, 8 img), 256 thr.
// LDS rows stride 40 halves (80B, 16B-aligned reads).
// ---------------------------------------------------------------------------
#define ABUF_H 2560    // 64*40
#define BBUF_H 5120    // 128*40
#define BUF_H  15360   // AHI+ALO+BHI+BLO
template <bool FIRST>
__global__ __launch_bounds__(256, 2) void conv_mfma(
    const float* __restrict__ src, const float* __restrict__ tgt,
    const float* __restrict__ ctxb, const float* __restrict__ w,
    const float* __restrict__ bias, float* __restrict__ ychunk,
    float* __restrict__ nrm_parts, int c0) {
    __shared__ __align__(16) _Float16 lds[2 * BUF_H];   // 61440 B

    int cb = blockIdx.x, pb = blockIdx.y, img = blockIdx.z;
    int n0 = pb * 64, m0g = c0 + cb * 128;
    const float* feat = (img < 4) ? src + (size_t)img * CIN * HW
                                  : tgt + (size_t)(img - 4) * CIN * HW;
    const float* ctxi = ctxb + (size_t)img * CCTX * HW;
    int tid = threadIdx.x;
    int aq = tid & 15, ar = tid >> 4;        // pix-quad, k-pair
    int brow = tid >> 1, bh_ = tid & 1;      // chan row, k-half(16)

    float4 xa[2], xb[4];
    auto loadA = [&](int k0) {
#pragma unroll
        for (int j = 0; j < 2; ++j) {
            int k = k0 + ar * 2 + j;
            if (k < CIN)       xa[j] = *(const float4*)(feat + (size_t)k * HW + n0 + aq * 4);
            else if (k < CALL) xa[j] = *(const float4*)(ctxi + (size_t)(k - CIN) * HW + n0 + aq * 4);
            else               xa[j] = make_float4(0.f, 0.f, 0.f, 0.f);
        }
    };
    auto loadB = [&](int k0) {
#pragma unroll
        for (int i = 0; i < 4; ++i) {
            int k = k0 + bh_ * 16 + i * 4;
            xb[i] = (k < CALL) ? *(const float4*)(w + (size_t)(m0g + brow) * CALL + k)
                               : make_float4(0.f, 0.f, 0.f, 0.f);
        }
    };
    auto storeLDS = [&](int b) {
        _Float16* Ah = lds + b * BUF_H;
        _Float16* Al = Ah + ABUF_H;
        _Float16* Bh = Al + ABUF_H;
        _Float16* Bl = Bh + BBUF_H;
#pragma unroll
        for (int p = 0; p < 4; ++p) {
            half2_t h, l;
            split2(f4get(xa[0], p), f4get(xa[1], p), h, l);
            int row = aq * 4 + p;
            *(half2_t*)(Ah + row * 40 + ar * 2) = h;
            *(half2_t*)(Al + row * 40 + ar * 2) = l;
        }
#pragma unroll
        for (int i = 0; i < 4; ++i) {
            half4_t h, l;
            split4(xb[i], h, l);
            *(half4_t*)(Bh + brow * 40 + bh_ * 16 + i * 4) = h;
            *(half4_t*)(Bl + brow * 40 + bh_ * 16 + i * 4) = l;
        }
    };

    int lane = tid & 63, wv4 = tid >> 6;
    int wm = wv4 >> 1, wn = wv4 & 1;
    int frow = lane & 15, kcol = (lane >> 4) * 8;

    f32x4 acc[2][4] = {};
    const int NT = 33;   // ceil(1052/32)
    loadA(0); loadB(0); storeLDS(0);
    __syncthreads();
    for (int t = 0; t < NT; ++t) {
        if (t + 1 < NT) { loadA((t + 1) * 32); loadB((t + 1) * 32); }
        const _Float16* Ah = lds + (t & 1) * BUF_H;
        const _Float16* Al = Ah + ABUF_H;
        const _Float16* Bh = Al + ABUF_H;
        const _Float16* Bl = Bh + BBUF_H;
        half8 ah[2], alr[2], bhr[4], blr[4];
#pragma unroll
        for (int fm = 0; fm < 2; ++fm) {
            int r = wm * 32 + fm * 16 + frow;
            ah[fm]  = *(const half8*)(Ah + r * 40 + kcol);
            alr[fm] = *(const half8*)(Al + r * 40 + kcol);
        }
#pragma unroll
        for (int fn = 0; fn < 4; ++fn) {
            int r = wn * 64 + fn * 16 + frow;
            bhr[fn] = *(const half8*)(Bh + r * 40 + kcol);
            blr[fn] = *(const half8*)(Bl + r * 40 + kcol);
        }
#pragma unroll
        for (int fm = 0; fm < 2; ++fm)
#pragma unroll
            for (int fn = 0; fn < 4; ++fn) {
                acc[fm][fn] = __builtin_amdgcn_mfma_f32_16x16x32_f16(ah[fm],  bhr[fn], acc[fm][fn], 0, 0, 0);
                acc[fm][fn] = __builtin_amdgcn_mfma_f32_16x16x32_f16(ah[fm],  blr[fn], acc[fm][fn], 0, 0, 0);
                acc[fm][fn] = __builtin_amdgcn_mfma_f32_16x16x32_f16(alr[fm], bhr[fn], acc[fm][fn], 0, 0, 0);
            }
        if (t + 1 < NT) storeLDS((t + 1) & 1);
        __syncthreads();
    }

    // epilogue: bias+relu, LDS bounce to coalesced Y store, nrm partials
    float* ybounce = (float*)lds;           // [64][132]
    float* ns = ybounce + 64 * 132;         // [2][64]
    float psum[2][4] = {};
#pragma unroll
    for (int fm = 0; fm < 2; ++fm)
#pragma unroll
        for (int fn = 0; fn < 4; ++fn) {
            int chan_l = wn * 64 + fn * 16 + (lane & 15);
            float bv = bias[m0g + chan_l];
#pragma unroll
            for (int r = 0; r < 4; ++r) {
                float v = fmaxf(acc[fm][fn][r] + bv, 0.f);
                int pix_l = wm * 32 + fm * 16 + (lane >> 4) * 4 + r;
                ybounce[pix_l * 132 + chan_l] = v;
                psum[fm][r] = fmaf(v, v, psum[fm][r]);
            }
        }
#pragma unroll
    for (int off = 1; off <= 8; off <<= 1)
#pragma unroll
        for (int fm = 0; fm < 2; ++fm)
#pragma unroll
            for (int r = 0; r < 4; ++r)
                psum[fm][r] = psum[fm][r] + __shfl_xor(psum[fm][r], off);
    if ((lane & 15) == 0) {
#pragma unroll
        for (int fm = 0; fm < 2; ++fm)
#pragma unroll
            for (int r = 0; r < 4; ++r)
                ns[wn * 64 + wm * 32 + fm * 16 + (lane >> 4) * 4 + r] = psum[fm][r];
    }
    __syncthreads();
    {
        int row = tid >> 2, seg = tid & 3;
        float* yp = ychunk + ((size_t)img * HW + n0 + row) * CCHNK + cb * 128 + seg * 32;
#pragma unroll
        for (int i = 0; i < 8; ++i)
            *(float4*)(yp + i * 4) = *(float4*)(ybounce + row * 132 + seg * 32 + i * 4);
    }
    if (tid < 64) {
        float sv = ns[tid] + ns[64 + tid];
        float* np = nrm_parts + ((size_t)img * 4 + cb) * HW + n0 + tid;
        if (FIRST) *np = sv; else *np += sv;
    }
}

// ---------------------------------------------------------------------------
// Kernel 4: correlation via MFMA, tile t=64 x s=128, K=512, BK=32, dbuf.
// MODE 0: store; 1: accumulate; 2: accumulate+normalize+max partials.
// grid (8 s-blk, 16 t-blk, 4 b), 256 thr.
// ---------------------------------------------------------------------------
template <int MODE>
__global__ __launch_bounds__(256, 2) void corr_mfma(
    const float* __restrict__ ychunk, const float* __restrict__ nrm_sq,
    float* __restrict__ corrT, float* __restrict__ spar, float* __restrict__ tpar) {
    __shared__ __align__(16) _Float16 lds[2 * BUF_H];

    int sb = blockIdx.x, tb = blockIdx.y, b = blockIdx.z;
    int t0 = tb * 64, s0 = sb * 128;
    const float* ytg = ychunk + (size_t)(4 + b) * HW * CCHNK;
    const float* ysr = ychunk + (size_t)b * HW * CCHNK;
    int tid = threadIdx.x;
    int arow = tid >> 2, akq = tid & 3;      // t row, k-octet
    int brow = tid >> 1, bh_ = tid & 1;      // s row, k-half

    float4 xa[2], xb[4];
    auto loadAB = [&](int k0) {
#pragma unroll
        for (int i = 0; i < 2; ++i)
            xa[i] = *(const float4*)(ytg + (size_t)(t0 + arow) * CCHNK + k0 + akq * 8 + i * 4);
#pragma unroll
        for (int i = 0; i < 4; ++i)
            xb[i] = *(const float4*)(ysr + (size_t)(s0 + brow) * CCHNK + k0 + bh_ * 16 + i * 4);
    };
    auto storeLDS = [&](int bb) {
        _Float16* Ah = lds + bb * BUF_H;
        _Float16* Al = Ah + ABUF_H;
        _Float16* Bh = Al + ABUF_H;
        _Float16* Bl = Bh + BBUF_H;
#pragma unroll
        for (int i = 0; i < 2; ++i) {
            half4_t h, l;
            split4(xa[i], h, l);
            *(half4_t*)(Ah + arow * 40 + akq * 8 + i * 4) = h;
            *(half4_t*)(Al + arow * 40 + akq * 8 + i * 4) = l;
        }
#pragma unroll
        for (int i = 0; i < 4; ++i) {
            half4_t h, l;
            split4(xb[i], h, l);
            *(half4_t*)(Bh + brow * 40 + bh_ * 16 + i * 4) = h;
            *(half4_t*)(Bl + brow * 40 + bh_ * 16 + i * 4) = l;
        }
    };

    int lane = tid & 63, wv4 = tid >> 6;
    int wm = wv4 >> 1, wn = wv4 & 1;
    int frow = lane & 15, kcol = (lane >> 4) * 8;

    f32x4 acc[2][4] = {};
    const int NT = CCHNK / 32;   // 16
    loadAB(0); storeLDS(0);
    __syncthreads();
    for (int t = 0; t < NT; ++t) {
        if (t + 1 < NT) loadAB((t + 1) * 32);
        const _Float16* Ah = lds + (t & 1) * BUF_H;
        const _Float16* Al = Ah + ABUF_H;
        const _Float16* Bh = Al + ABUF_H;
        const _Float16* Bl = Bh + BBUF_H;
        half8 ah[2], alr[2], bhr[4], blr[4];
#pragma unroll
        for (int fm = 0; fm < 2; ++fm) {
            int r = wm * 32 + fm * 16 + frow;
            ah[fm]  = *(const half8*)(Ah + r * 40 + kcol);
            alr[fm] = *(const half8*)(Al + r * 40 + kcol);
        }
#pragma unroll
        for (int fn = 0; fn < 4; ++fn) {
            int r = wn * 64 + fn * 16 + frow;
            bhr[fn] = *(const half8*)(Bh + r * 40 + kcol);
            blr[fn] = *(const half8*)(Bl + r * 40 + kcol);
        }
#pragma unroll
        for (int fm = 0; fm < 2; ++fm)
#pragma unroll
            for (int fn = 0; fn < 4; ++fn) {
                acc[fm][fn] = __builtin_amdgcn_mfma_f32_16x16x32_f16(ah[fm],  bhr[fn], acc[fm][fn], 0, 0, 0);
                acc[fm][fn] = __builtin_amdgcn_mfma_f32_16x16x32_f16(ah[fm],  blr[fn], acc[fm][fn], 0, 0, 0);
                acc[fm][fn] = __builtin_amdgcn_mfma_f32_16x16x32_f16(alr[fm], bhr[fn], acc[fm][fn], 0, 0, 0);
            }
        if (t + 1 < NT) storeLDS((t + 1) & 1);
        __syncthreads();
    }

    float rnt[2][4], rns[4];
    float rowmax[2][4] = {};
    float colmax[4] = {};
    if (MODE == 2) {
#pragma unroll
        for (int fm = 0; fm < 2; ++fm)
#pragma unroll
            for (int r = 0; r < 4; ++r) {
                int t = t0 + wm * 32 + fm * 16 + (lane >> 4) * 4 + r;
                rnt[fm][r] = 1.f / sqrtf(nrm_sq[(size_t)(4 + b) * HW + t] + 1e-6f);
            }
#pragma unroll
        for (int fn = 0; fn < 4; ++fn) {
            int s_ = s0 + wn * 64 + fn * 16 + (lane & 15);
            rns[fn] = 1.f / sqrtf(nrm_sq[(size_t)b * HW + s_] + 1e-6f);
        }
    }
#pragma unroll
    for (int fm = 0; fm < 2; ++fm)
#pragma unroll
        for (int r = 0; r < 4; ++r) {
            int t = t0 + wm * 32 + fm * 16 + (lane >> 4) * 4 + r;
            float* cp = corrT + ((size_t)b * HW + t) * HW + s0 + wn * 64 + (lane & 15);
#pragma unroll
            for (int fn = 0; fn < 4; ++fn) {
                float v = acc[fm][fn][r];
                if (MODE >= 1) v += cp[fn * 16];
                if (MODE == 2) {
                    v *= rnt[fm][r] * rns[fn];
                    rowmax[fm][r] = fmaxf(rowmax[fm][r], v);
                    colmax[fn] = fmaxf(colmax[fn], v);
                }
                cp[fn * 16] = v;
            }
        }
    if (MODE == 2) {
        float* rm = (float*)lds;
        float* cm = rm + 128;
#pragma unroll
        for (int off = 1; off <= 8; off <<= 1)
#pragma unroll
            for (int fm = 0; fm < 2; ++fm)
#pragma unroll
                for (int r = 0; r < 4; ++r)
                    rowmax[fm][r] = fmaxf(rowmax[fm][r], __shfl_xor(rowmax[fm][r], off));
        if ((lane & 15) == 0) {
#pragma unroll
            for (int fm = 0; fm < 2; ++fm)
#pragma unroll
                for (int r = 0; r < 4; ++r)
                    rm[wn * 64 + wm * 32 + fm * 16 + (lane >> 4) * 4 + r] = rowmax[fm][r];
        }
#pragma unroll
        for (int off = 16; off <= 32; off <<= 1)
#pragma unroll
            for (int fn = 0; fn < 4; ++fn)
                colmax[fn] = fmaxf(colmax[fn], __shfl_xor(colmax[fn], off));
        if ((lane >> 4) == 0) {
#pragma unroll
            for (int fn = 0; fn < 4; ++fn)
                cm[wv4 * 64 + fn * 16 + (lane & 15)] = colmax[fn];
        }
        __syncthreads();
        if (tid < 64)
            tpar[((size_t)b * 8 + sb) * HW + t0 + tid] = fmaxf(rm[tid], rm[64 + tid]);
        if (tid < 128) {
            int q = tid >> 6;
            float mv = fmaxf(cm[q * 64 + (tid & 63)], cm[(2 + q) * 64 + (tid & 63)]);
            spar[((size_t)b * 16 + tb) * HW + s0 + tid] = mv;
        }
    }
}

// ---------------------------------------------------------------------------
// Kernel 5: nrm_sq = sum of 4 chan-block partials
// ---------------------------------------------------------------------------
__global__ void nrm_reduce(const float* __restrict__ nrm_parts, float* __restrict__ nrm_sq) {
    int img = blockIdx.y;
    int p = blockIdx.x * 256 + threadIdx.x;
    float s = 0.f;
#pragma unroll
    for (int mb = 0; mb < 4; ++mb)
        s += nrm_parts[((size_t)img * 4 + mb) * HW + p];
    nrm_sq[img * HW + p] = s;
}

// ---------------------------------------------------------------------------
// Kernel 6: combine smax (16 t-blk partials) / tmax (8 s-blk partials)
// ---------------------------------------------------------------------------
__global__ void combine_max(const float* __restrict__ spar, const float* __restrict__ tpar,
                            float* __restrict__ smax, float* __restrict__ tmax) {
    int b = blockIdx.y;
    int i = blockIdx.x * 256 + threadIdx.x;
    float m = 0.f;
#pragma unroll
    for (int q = 0; q < 16; ++q) m = fmaxf(m, spar[((size_t)b * 16 + q) * HW + i]);
    smax[b * HW + i] = m;
    float m2 = 0.f;
#pragma unroll
    for (int q = 0; q < 8; ++q) m2 = fmaxf(m2, tpar[((size_t)b * 8 + q) * HW + i]);
    tmax[b * HW + i] = m2;
}

// ---------------------------------------------------------------------------
// Kernel 7: final — filter per tap row, separable bilinear, softmax-argmax.
// j-invariant index math hoisted (j = tid&63 is constant across u).
// ---------------------------------------------------------------------------
__global__ __launch_bounds__(256) void final_kernel(const float* __restrict__ corrT,
                                                    const float* __restrict__ smax,
                                                    const float* __restrict__ tmax,
                                                    float* __restrict__ out) {
    __shared__ float vsh[1024];
    __shared__ float rbuf[16];
    int b = blockIdx.z;
    int typ = blockIdx.y;
    int txp = blockIdx.x;
    int tid = threadIdx.x;

    float fy = typ * (31.0f / 63.0f);
    int y0 = min((int)fy, 31); int y1 = min(y0 + 1, 31);
    float wy = fy - (float)y0;
    float fx = txp * (31.0f / 63.0f);
    int x0 = min((int)fx, 31); int x1 = min(x0 + 1, 31);
    float wx = fx - (float)x0;
    int tA = y0 * 32 + x0, tB = y0 * 32 + x1, tC = y1 * 32 + x0, tD = y1 * 32 + x1;
    const float* base = corrT + (size_t)b * HW * HW;
    const float* rA = base + (size_t)tA * HW;
    const float* rB = base + (size_t)tB * HW;
    const float* rC = base + (size_t)tC * HW;
    const float* rD = base + (size_t)tD * HW;
    float tmA_ = tmax[b * HW + tA]; if (tmA_ == 0.f) tmA_ = 1e-30f;
    float tmB_ = tmax[b * HW + tB]; if (tmB_ == 0.f) tmB_ = 1e-30f;
    float tmC_ = tmax[b * HW + tC]; if (tmC_ == 0.f) tmC_ = 1e-30f;
    float tmD_ = tmax[b * HW + tD]; if (tmD_ == 0.f) tmD_ = 1e-30f;
    float itA = 1.f / tmA_, itB = 1.f / tmB_, itC = 1.f / tmC_, itD = 1.f / tmD_;
    float wA = (1.f - wy) * (1.f - wx), wB = (1.f - wy) * wx;
    float wC = wy * (1.f - wx), wD = wy * wx;
#pragma unroll
    for (int u = 0; u < 4; ++u) {
        int s = u * 256 + tid;
        float sm = smax[b * HW + s]; if (sm == 0.f) sm = 1e-30f;
        float is = 1.f / sm;
        float a = rA[s]; a = a * a * a * is * itA;
        float b2 = rB[s]; b2 = b2 * b2 * b2 * is * itB;
        float c2 = rC[s]; c2 = c2 * c2 * c2 * is * itC;
        float d2 = rD[s]; d2 = d2 * d2 * d2 * is * itD;
        vsh[s] = wA * a + wB * b2 + wC * c2 + wD * d2;
    }
    __syncthreads();

    // hoisted j-column values (j = tid & 63, invariant across u)
    int jx = tid & 63;
    int wvq = tid >> 6;
    float gxx = jx * (31.0f / 63.0f);
    int sx0 = min((int)gxx, 31), sx1 = min(sx0 + 1, 31);
    float wxx = gxx - (float)sx0, iwxx = 1.f - wxx;
    float xnj = jx * (2.0f / 63.0f) - 1.0f;

    float cv[16];
    float lmax = -1e30f;
#pragma unroll
    for (int u = 0; u < 16; ++u) {
        int iy = u * 4 + wvq;
        float gy = iy * (31.0f / 63.0f);
        int sy0 = min((int)gy, 31), sy1 = min(sy0 + 1, 31);
        float wyy = gy - (float)sy0;
        float r0 = vsh[sy0 * 32 + sx0] * iwxx + vsh[sy0 * 32 + sx1] * wxx;
        float r1 = vsh[sy1 * 32 + sx0] * iwxx + vsh[sy1 * 32 + sx1] * wxx;
        cv[u] = (r0 * (1.f - wyy) + r1 * wyy) * 50.0f;
        lmax = fmaxf(lmax, cv[u]);
    }
#pragma unroll
    for (int off = 32; off >= 1; off >>= 1) lmax = fmaxf(lmax, __shfl_down(lmax, off));
    int lane = tid & 63;
    if (lane == 0) rbuf[wvq] = lmax;
    __syncthreads();
    if (tid == 0) {
        float m = rbuf[0];
        for (int i = 1; i < 4; ++i) m = fmaxf(m, rbuf[i]);
        rbuf[0] = m;
    }
    __syncthreads();
    float m = rbuf[0];

    float e0 = 0.f, ex = 0.f, ey = 0.f;
#pragma unroll
    for (int u = 0; u < 16; ++u) {
        int iy = u * 4 + wvq;
        float e = __expf(cv[u] - m);
        e0 += e;
        ex = fmaf(e, xnj, ex);
        ey = fmaf(e, iy * (2.0f / 63.0f) - 1.0f, ey);
    }
#pragma unroll
    for (int off = 32; off >= 1; off >>= 1) {
        e0 += __shfl_down(e0, off);
        ex += __shfl_down(ex, off);
        ey += __shfl_down(ey, off);
    }
    if (lane == 0) { rbuf[4 + wvq] = e0; rbuf[8 + wvq] = ex; rbuf[12 + wvq] = ey; }
    __syncthreads();
    if (tid == 0) {
        float s0 = rbuf[4] + rbuf[5] + rbuf[6] + rbuf[7];
        float sx = rbuf[8] + rbuf[9] + rbuf[10] + rbuf[11];
        float sy = rbuf[12] + rbuf[13] + rbuf[14] + rbuf[15];
        float gx = sx / s0, gy = sy / s0;
        float mx = (gx + 1.f) * 31.5f;
        float my = (gy + 1.f) * 31.5f;
        out[(((size_t)b * 2 + 0) * 64 + typ) * 64 + txp] = mx - (float)txp;
        out[(((size_t)b * 2 + 1) * 64 + typ) * 64 + txp] = my - (float)typ;
    }
}

// ---------------------------------------------------------------------------
// Workspace (floats), total 8,773,632 = 33.47 MiB — proven layout.
//   corrT 4194304 | nrm_parts 32768 | tpar 32768 | nrm_sq 8192 | smax 4096
//   spar 65536 | tmax 4096 | pnorm 8192 | ctxbuf 229376 | ychunk 4194304
// pnorm_parts aliases ychunk (consumed before conv writes it).
// ---------------------------------------------------------------------------
extern "C" void kernel_launch(void* const* d_in, const int* in_sizes, int n_in,
                              void* d_out, int out_size, void* d_ws, size_t ws_size,
                              hipStream_t stream) {
    const float* src  = (const float*)d_in[0];
    const float* tgt  = (const float*)d_in[1];
    const float* sw   = (const float*)d_in[2];
    const float* sb   = (const float*)d_in[3];
    float* out = (float*)d_out;

    float* corrT      = (float*)d_ws;
    float* nrm_parts  = corrT + 4194304;
    float* tpar       = nrm_parts + 32768;
    float* nrm_sq     = nrm_parts + 65536;
    float* smax       = nrm_sq + 8192;
    float* spar       = smax + 4096;
    float* tmax       = spar + 65536;
    float* pnorm      = tmax + 4096;
    float* ctxbuf     = pnorm + 8192;
    float* ychunk     = ctxbuf + 229376;
    float* pparts     = ychunk;             // alias, dead before conv chunk 0

    pnorm_part<<<dim3(8, 16, 4), 64, 0, stream>>>(src, tgt, pparts);
    pnorm_combine<<<dim3(8, 16), 64, 0, stream>>>(pparts, pnorm);
    ctx_kernel<<<dim3(8, 32), 896, 0, stream>>>(src, tgt, pnorm, ctxbuf);

    conv_mfma<true><<<dim3(4, 16, 8), 256, 0, stream>>>(src, tgt, ctxbuf, sw, sb,
                                                        ychunk, nrm_parts, 0);
    corr_mfma<0><<<dim3(8, 16, 4), 256, 0, stream>>>(ychunk, nrm_sq, corrT, spar, tpar);
    for (int c = 1; c < 3; ++c) {
        conv_mfma<false><<<dim3(4, 16, 8), 256, 0, stream>>>(src, tgt, ctxbuf, sw, sb,
                                                             ychunk, nrm_parts, c * CCHNK);
        corr_mfma<1><<<dim3(8, 16, 4), 256, 0, stream>>>(ychunk, nrm_sq, corrT, spar, tpar);
    }
    conv_mfma<false><<<dim3(4, 16, 8), 256, 0, stream>>>(src, tgt, ctxbuf, sw, sb,
                                                         ychunk, nrm_parts, 3 * CCHNK);
    nrm_reduce<<<dim3(4, 8), 256, 0, stream>>>(nrm_parts, nrm_sq);
    corr_mfma<2><<<dim3(8, 16, 4), 256, 0, stream>>>(ychunk, nrm_sq, corrT, spar, tpar);

    combine_max<<<dim3(4, 4), 256, 0, stream>>>(spar, tpar, smax, tmax);
    final_kernel<<<dim3(64, 64, 4), 256, 0, stream>>>(corrT, smax, tmax, out);
}